// Round 2
// 252.895 us; speedup vs baseline: 1.0349x; 1.0349x over previous
//
#include <hip/hip_runtime.h>
#include <cstdint>
#include <cstddef>

// ---------- types ----------
typedef float v4f  __attribute__((ext_vector_type(4)));
typedef __bf16 v8bf __attribute__((ext_vector_type(8)));
typedef __bf16 v4bf __attribute__((ext_vector_type(4)));

#define M_TOT 32768   // 8*64*64 tokens
#define KDIM  512
#define NQKV  1536
#define NPROJ 512

__device__ __constant__ float c_invf[8] = {
  1.f, 0.31622776601683794f, 0.1f, 0.031622776601683794f,
  0.01f, 0.0031622776601683794f, 0.001f, 0.00031622776601683794f };

__device__ __forceinline__ void async_copy16(const void* g, void* l) {
  __builtin_amdgcn_global_load_lds((const __attribute__((address_space(1))) void*)g,
                                   (__attribute__((address_space(3))) void*)l, 16, 0, 0);
}

// ---------- cast x -> bf16 ----------
__global__ void cast_x_kernel(const float* __restrict__ in, __bf16* __restrict__ out, int n8) {
  int i = blockIdx.x * blockDim.x + threadIdx.x;
  if (i >= n8) return;
  const float4* p = (const float4*)in + (size_t)i * 2;
  float4 a = p[0], b = p[1];
  v8bf r = { (__bf16)a.x, (__bf16)a.y, (__bf16)a.z, (__bf16)a.w,
             (__bf16)b.x, (__bf16)b.y, (__bf16)b.z, (__bf16)b.w };
  *(v8bf*)(out + (size_t)i * 8) = r;
}

// ---------- tiled transpose+cast: w[K][N] -> wt[N][K] bf16 ----------
__global__ __launch_bounds__(256) void transpose_cast_kernel(
    const float* __restrict__ w, __bf16* __restrict__ wt, int K, int N) {
  __shared__ __bf16 t[64 * 72];
  const int tid = threadIdx.x;
  const int n0 = blockIdx.x * 64, k0 = blockIdx.y * 64;
#pragma unroll
  for (int i = 0; i < 16; ++i) {
    int e = i * 256 + tid;
    int kk = e >> 6, nn = e & 63;
    t[nn * 72 + kk] = (__bf16)w[(size_t)(k0 + kk) * N + n0 + nn];
  }
  __syncthreads();
#pragma unroll
  for (int i = 0; i < 2; ++i) {
    int e = i * 256 + tid;
    int nn = e >> 3, kc = e & 7;
    *(v8bf*)&wt[(size_t)(n0 + nn) * K + k0 + kc * 8] = *(const v8bf*)&t[nn * 72 + kc * 8];
  }
}

// ---------- fused: qkv GEMM + rope + windowed attention ----------
// block: 256 thr (4 waves). tile: 128 tokens (2 windows) x 192 cols (2 heads).
// wave w: window wl=w>>1, head-local hl=w&1 -> owns 64 tok x 96 cols, and the
// full attention for its (window, head).
// grid (8, 256); XCD-chunked remap inside: hp = by&7, mt = (by&~7)|bx, so the
// 8 blocks sharing an A-tile sit at linear ids spaced 8 apart (same XCD under
// the %8 round-robin) and within one 64-id launch window -> A-tile L2 reuse.
// LDS: staging As[0,16384) Bs[16384,40960); after K-loop: 4 regions x 12288 B
//   { q 64x32 | k 64x32 | v 32x64 }, all power-of-2 pitch with XOR
//   group-of-8 swizzles (bank-uniform reads). P (64x64, swizzled) aliases
//   the dead q+k area of the own region. 49152 B total -> 3 blocks/CU.
#define REG_STRIDE 12288

__global__ __launch_bounds__(256, 3) void gemm_qkv_attn(
    const __bf16* __restrict__ A,    // [M_TOT][512] bf16 (token order)
    const __bf16* __restrict__ Bt,   // [1536][512] bf16
    const float* __restrict__ bias,  // [1536]
    __bf16* __restrict__ attn_out)   // [512*64][512] window-row order
{
  __shared__ __align__(16) char smem[49152];
  __bf16* As = (__bf16*)smem;
  __bf16* Bs = (__bf16*)(smem + 16384);

  const int tid  = threadIdx.x;
  const int lane = tid & 63;
  const int wave = tid >> 6;
  const int lrow = lane & 15, quad = lane >> 4;
  // XCD-chunked work remap (bijective): same-mt blocks share an XCD L2.
  const int hp   = blockIdx.y & 7;               // head pair 0..7
  const int mt   = (blockIdx.y & ~7) | blockIdx.x;  // m-tile 0..255
  const int wl   = wave >> 1, hl = wave & 1;
  const int head = hp * 2 + hl;

  // window token bases
  int mbase[2];
#pragma unroll
  for (int l = 0; l < 2; ++l) {
    int w  = mt * 2 + l;
    int b  = w >> 6, Wr = (w >> 3) & 7, Wc = w & 7;
    mbase[l] = b * 4096 + Wr * 512 + Wc * 8;
  }

  // hoisted staging pointers (advance by 64 per K-iter)
  const __bf16* aptr[4]; __bf16* adst[4];
  const __bf16* bptr[6]; __bf16* bdst[6];
#pragma unroll
  for (int i = 0; i < 4; ++i) {
    int s = i * 256 + tid;
    int row = s >> 3, c = s & 7, qc = c ^ (row & 7);
    int tok = row & 63;
    int m = mbase[row >> 6] + ((tok >> 3) << 6) + (tok & 7);
    aptr[i] = A + (size_t)m * KDIM + qc * 8;
    adst[i] = &As[(i * 256 + (tid & ~63)) * 8];
  }
#pragma unroll
  for (int i = 0; i < 6; ++i) {
    int s = i * 256 + tid;
    int rl = s >> 3, c = s & 7, qc = c ^ (rl & 7);
    int sel = rl >> 6, rem = rl & 63;
    int grow = sel * 512 + (hp * 2 + (rem >> 5)) * 32 + (rem & 31);
    bptr[i] = Bt + (size_t)grow * KDIM + qc * 8;
    bdst[i] = &Bs[(i * 256 + (tid & ~63)) * 8];
  }

  v4f acc[4][6] = {};

  for (int k0 = 0; k0 < KDIM; k0 += 64) {
#pragma unroll
    for (int i = 0; i < 4; ++i) { async_copy16(aptr[i], adst[i]); aptr[i] += 64; }
#pragma unroll
    for (int i = 0; i < 6; ++i) { async_copy16(bptr[i], bdst[i]); bptr[i] += 64; }
    __syncthreads();
#pragma unroll
    for (int kb = 0; kb < 2; ++kb) {
      int sx = (((kb << 2) | quad) ^ (lrow & 7)) * 8;
      v8bf af[4], bfr[6];
#pragma unroll
      for (int mi = 0; mi < 4; ++mi)
        af[mi] = *(const v8bf*)&As[(wl * 64 + mi * 16 + lrow) * 64 + sx];
#pragma unroll
      for (int j = 0; j < 6; ++j)
        bfr[j] = *(const v8bf*)&Bs[((j >> 1) * 64 + hl * 32 + (j & 1) * 16 + lrow) * 64 + sx];
#pragma unroll
      for (int mi = 0; mi < 4; ++mi)
#pragma unroll
        for (int j = 0; j < 6; ++j)
          acc[mi][j] = __builtin_amdgcn_mfma_f32_16x16x32_bf16(af[mi], bfr[j], acc[mi][j], 0, 0, 0);
    }
    __syncthreads();   // last iter: also protects region aliasing below
  }

  // ---- epilogue: bias + rope -> wave-private LDS region (no barriers) ----
  // qL/kL: [64 tok][32 hd], pitch 32, hd-group swizzle g^=((tok>>2)&3)
  // vL:    [32 hd][64 tok], pitch 64, tok-group swizzle g^=(hd&7)
  __bf16* reg = (__bf16*)(smem + wave * REG_STRIDE);
  __bf16* qL = reg;
  __bf16* kL = reg + 64 * 32;
  __bf16* vL = reg + 2 * 64 * 32;

  // Hoisted sincos: angle p*invf takes only 4 distinct values per lane per
  // axis, identical for q and k:
  //   hd<16 : p = tok>>3 = mi*2 + (quad>>1)    (independent of r)
  //   hd>=16: p = tok&7  = (quad&1)*4 + r      (independent of mi)
  // invf = c_invf[lrow&7] for both nh halves. 8 sincos replace 64.
  {
    const float invf = c_invf[lrow & 7];
    float cvh[4], svh[4], cvw[4], svw[4];
#pragma unroll
    for (int mi = 0; mi < 4; ++mi)
      __sincosf((float)(mi * 2 + (quad >> 1)) * invf, &svh[mi], &cvh[mi]);
#pragma unroll
    for (int r = 0; r < 4; ++r)
      __sincosf((float)((quad & 1) * 4 + r) * invf, &svw[r], &cvw[r]);

#pragma unroll
    for (int j = 0; j < 4; ++j) {          // q (j 0,1), k (j 2,3)
      int sel = j >> 1, nh = j & 1;
      int hd  = nh * 16 + lrow;
      int g   = nh * 2 + (lrow >> 3);      // hd-group (0..3)
      float bv = bias[sel * 512 + head * 32 + hd];
      __bf16* dst = sel ? kL : qL;
#pragma unroll
      for (int mi = 0; mi < 4; ++mi) {
#pragma unroll
        for (int r = 0; r < 4; ++r) {
          int tok = mi * 16 + quad * 4 + r;
          float val = acc[mi][j][r] + bv;
          float partner = __shfl_xor(val, 8);
          float cv = nh ? cvw[r] : cvh[mi];
          float sv = nh ? svw[r] : svh[mi];
          float rh = (lrow & 8) ? partner : -partner;
          val = val * cv + rh * sv;
          if (sel == 0) val *= 0.17677669529663689f;
          // (tok>>2)&3 == quad here
          dst[tok * 32 + ((g ^ quad) << 3) + (lrow & 7)] = (__bf16)val;
        }
      }
    }
  }
#pragma unroll
  for (int j = 4; j < 6; ++j) {          // v transposed [hd][tok]
    int hd = (j - 4) * 16 + lrow;        // 0..31; hd&7 == lrow&7
    float bv = bias[1024 + head * 32 + hd];
#pragma unroll
    for (int mi = 0; mi < 4; ++mi) {
      v4bf pk;
#pragma unroll
      for (int r = 0; r < 4; ++r) pk[r] = (__bf16)(acc[mi][j][r] + bv);
      int gt = mi * 2 + (quad >> 1);     // tok-group of tok0 = mi*16+quad*4
      *(v4bf*)&vL[hd * 64 + ((gt ^ (lrow & 7)) << 3) + (quad & 1) * 4] = pk;
    }
  }

  // ---- attention (wave-private) ----
  const int sq = (quad ^ (lrow >> 2)) << 3;   // q/k read swizzle (row-const)
  v8bf qf[4], kf[4];
#pragma unroll
  for (int mi = 0; mi < 4; ++mi)
    qf[mi] = *(const v8bf*)&qL[(mi * 16 + lrow) * 32 + sq];
#pragma unroll
  for (int ni = 0; ni < 4; ++ni)
    kf[ni] = *(const v8bf*)&kL[(ni * 16 + lrow) * 32 + sq];

  v4f S[4][4] = {};
#pragma unroll
  for (int mi = 0; mi < 4; ++mi)
#pragma unroll
    for (int ni = 0; ni < 4; ++ni)
      S[mi][ni] = __builtin_amdgcn_mfma_f32_16x16x32_bf16(qf[mi], kf[ni], S[mi][ni], 0, 0, 0);

#pragma unroll
  for (int mi = 0; mi < 4; ++mi) {
#pragma unroll
    for (int r = 0; r < 4; ++r) {
      float mx = S[mi][0][r];
#pragma unroll
      for (int ni = 1; ni < 4; ++ni) mx = fmaxf(mx, S[mi][ni][r]);
      for (int d = 1; d < 16; d <<= 1) mx = fmaxf(mx, __shfl_xor(mx, d));
      float sum = 0.f;
#pragma unroll
      for (int ni = 0; ni < 4; ++ni) {
        float e = __expf(S[mi][ni][r] - mx);
        S[mi][ni][r] = e; sum += e;
      }
      for (int d = 1; d < 16; d <<= 1) sum += __shfl_xor(sum, d);
      float inv = 1.f / sum;
#pragma unroll
      for (int ni = 0; ni < 4; ++ni) S[mi][ni][r] *= inv;
    }
  }

  // P (C-layout -> A-layout) through own region (aliases dead q+k)
  // P: [64 tok][64 col], pitch 64, col-group swizzle g^=(tok&7)
  __bf16* P = reg;
#pragma unroll
  for (int mi = 0; mi < 4; ++mi)
#pragma unroll
    for (int ni = 0; ni < 4; ++ni)
#pragma unroll
      for (int r = 0; r < 4; ++r) {
        int tok = mi * 16 + quad * 4 + r;
        int gc  = ni * 2 + (lrow >> 3);
        P[tok * 64 + ((gc ^ (tok & 7)) << 3) + (lrow & 7)] = (__bf16)S[mi][ni][r];
      }

  v8bf pf[4][2], vf[2][2];
#pragma unroll
  for (int mi = 0; mi < 4; ++mi)
#pragma unroll
    for (int kc = 0; kc < 2; ++kc) {
      int row = mi * 16 + lrow;          // row&7 == lrow&7
      pf[mi][kc] = *(const v8bf*)&P[row * 64 + (((kc * 4 + quad) ^ (lrow & 7)) << 3)];
    }
#pragma unroll
  for (int kc = 0; kc < 2; ++kc)
#pragma unroll
    for (int nj = 0; nj < 2; ++nj) {
      int hd = nj * 16 + lrow;           // hd&7 == lrow&7
      vf[kc][nj] = *(const v8bf*)&vL[hd * 64 + (((kc * 4 + quad) ^ (lrow & 7)) << 3)];
    }

  v4f o[4][2] = {};
#pragma unroll
  for (int mi = 0; mi < 4; ++mi)
#pragma unroll
    for (int nj = 0; nj < 2; ++nj)
#pragma unroll
      for (int kc = 0; kc < 2; ++kc)
        o[mi][nj] = __builtin_amdgcn_mfma_f32_16x16x32_bf16(pf[mi][kc], vf[kc][nj], o[mi][nj], 0, 0, 0);

  const int gwin = mt * 2 + wl;
#pragma unroll
  for (int mi = 0; mi < 4; ++mi)
#pragma unroll
    for (int nj = 0; nj < 2; ++nj)
#pragma unroll
      for (int r = 0; r < 4; ++r) {
        int tok = mi * 16 + quad * 4 + r;
        int ch  = head * 32 + nj * 16 + lrow;
        attn_out[((size_t)gwin * 64 + tok) * 512 + ch] = (__bf16)o[mi][nj][r];
      }
}

// ---------- GEMM2: out = attn_out @ proj_w + b, permuted store ----------
// 256x128 tile, wave = 64 rows x 128 cols. grid (4 n FAST, 128 m) = 512 blocks.
__global__ __launch_bounds__(256) void gemm_proj(
    const __bf16* __restrict__ A,    // [M_TOT][512] window-row order
    const __bf16* __restrict__ Bt,   // [512][512]
    const float* __restrict__ bias,  // [512]
    float* __restrict__ out)         // [8][64][64][512] spatial
{
  __shared__ __align__(16) char smem[49152];
  __bf16* As = (__bf16*)smem;                  // 256x64
  __bf16* Bs = (__bf16*)(smem + 32768);        // 128x64
  const int tid  = threadIdx.x;
  const int lane = tid & 63;
  const int wave = tid >> 6;
  const int n0 = blockIdx.x * 128, m0 = blockIdx.y * 256;
  const int lrow = lane & 15, quad = lane >> 4;

  const __bf16* aptr[8]; __bf16* adst[8];
  const __bf16* bptr[4]; __bf16* bdst[4];
#pragma unroll
  for (int i = 0; i < 8; ++i) {
    int s = i * 256 + tid;
    int row = s >> 3, c = s & 7, qc = c ^ (row & 7);
    aptr[i] = A + (size_t)(m0 + row) * KDIM + qc * 8;
    adst[i] = &As[(i * 256 + (tid & ~63)) * 8];
  }
#pragma unroll
  for (int i = 0; i < 4; ++i) {
    int s = i * 256 + tid;
    int row = s >> 3, c = s & 7, qc = c ^ (row & 7);
    bptr[i] = Bt + (size_t)(n0 + row) * KDIM + qc * 8;
    bdst[i] = &Bs[(i * 256 + (tid & ~63)) * 8];
  }

  v4f acc[4][8] = {};

  for (int k0 = 0; k0 < KDIM; k0 += 64) {
#pragma unroll
    for (int i = 0; i < 8; ++i) { async_copy16(aptr[i], adst[i]); aptr[i] += 64; }
#pragma unroll
    for (int i = 0; i < 4; ++i) { async_copy16(bptr[i], bdst[i]); bptr[i] += 64; }
    __syncthreads();
#pragma unroll
    for (int kb = 0; kb < 2; ++kb) {
      int sx = (((kb << 2) | quad) ^ (lrow & 7)) * 8;
      v8bf af[4], bfr[8];
#pragma unroll
      for (int mi = 0; mi < 4; ++mi)
        af[mi] = *(const v8bf*)&As[(wave * 64 + mi * 16 + lrow) * 64 + sx];
#pragma unroll
      for (int ni = 0; ni < 8; ++ni)
        bfr[ni] = *(const v8bf*)&Bs[(ni * 16 + lrow) * 64 + sx];
#pragma unroll
      for (int mi = 0; mi < 4; ++mi)
#pragma unroll
        for (int ni = 0; ni < 8; ++ni)
          acc[mi][ni] = __builtin_amdgcn_mfma_f32_16x16x32_bf16(af[mi], bfr[ni], acc[mi][ni], 0, 0, 0);
    }
    __syncthreads();
  }

  const int mb = m0 + wave * 64;
#pragma unroll
  for (int ni = 0; ni < 8; ++ni) {
    int n = n0 + ni * 16 + lrow;
    float bv = bias[n];
#pragma unroll
    for (int mi = 0; mi < 4; ++mi) {
#pragma unroll
      for (int r = 0; r < 4; ++r) {
        int m    = mb + mi * 16 + quad * 4 + r;
        int win  = m >> 6, tok = m & 63;
        int bb   = win >> 6;
        int hblk = (win >> 3) & 7, wblk = win & 7;
        int h    = hblk * 8 + (tok >> 3);
        int w    = wblk * 8 + (tok & 7);
        out[(((size_t)bb * 64 + h) * 64 + w) * 512 + n] = acc[mi][ni][r] + bv;
      }
    }
  }
}

// ---------- launcher ----------
extern "C" void kernel_launch(void* const* d_in, const int* in_sizes, int n_in,
                              void* d_out, int out_size, void* d_ws, size_t ws_size,
                              hipStream_t stream) {
  (void)in_sizes; (void)n_in; (void)out_size; (void)ws_size;
  const float* x      = (const float*)d_in[0];
  const float* qkv_w  = (const float*)d_in[1];
  const float* qkv_b  = (const float*)d_in[2];
  // d_in[3]=kv_w, d_in[4]=kv_b: dead code in reference (hy_kv unused)
  const float* proj_w = (const float*)d_in[5];
  const float* proj_b = (const float*)d_in[6];
  float* out = (float*)d_out;

  char* ws = (char*)d_ws;
  size_t off = 0;
  auto alloc = [&](size_t bytes) {
    char* p = ws + off;
    off += (bytes + 255) & ~(size_t)255;
    return (void*)p;
  };
  __bf16* xb       = (__bf16*)alloc((size_t)M_TOT * KDIM * 2);
  __bf16* qkv_wt   = (__bf16*)alloc((size_t)NQKV * KDIM * 2);
  __bf16* proj_wt  = (__bf16*)alloc((size_t)KDIM * KDIM * 2);
  __bf16* attn_out = (__bf16*)alloc((size_t)M_TOT * KDIM * 2);

  cast_x_kernel<<<dim3(M_TOT * KDIM / 8 / 256), dim3(256), 0, stream>>>(
      x, xb, M_TOT * KDIM / 8);
  transpose_cast_kernel<<<dim3(NQKV / 64, KDIM / 64), dim3(256), 0, stream>>>(
      qkv_w, qkv_wt, KDIM, NQKV);
  transpose_cast_kernel<<<dim3(NPROJ / 64, KDIM / 64), dim3(256), 0, stream>>>(
      proj_w, proj_wt, KDIM, NPROJ);

  gemm_qkv_attn<<<dim3(8, 256), dim3(256), 0, stream>>>(
      xb, qkv_wt, qkv_b, attn_out);

  gemm_proj<<<dim3(4, 128), dim3(256), 0, stream>>>(
      attn_out, proj_wt, proj_b, out);
}

// Round 3
// 227.915 us; speedup vs baseline: 1.1484x; 1.1096x over previous
//
#include <hip/hip_runtime.h>
#include <cstdint>
#include <cstddef>

// ---------- types ----------
typedef float v4f  __attribute__((ext_vector_type(4)));
typedef __bf16 v8bf __attribute__((ext_vector_type(8)));
typedef __bf16 v4bf __attribute__((ext_vector_type(4)));

#define M_TOT 32768   // 8*64*64 tokens
#define KDIM  512
#define NQKV  1536
#define NPROJ 512

__device__ __constant__ float c_invf[8] = {
  1.f, 0.31622776601683794f, 0.1f, 0.031622776601683794f,
  0.01f, 0.0031622776601683794f, 0.001f, 0.00031622776601683794f };

__device__ __forceinline__ void async_copy16(const void* g, void* l) {
  __builtin_amdgcn_global_load_lds((const __attribute__((address_space(1))) void*)g,
                                   (__attribute__((address_space(3))) void*)l, 16, 0, 0);
}

// ---------- cast x -> bf16 (grid-stride) ----------
__global__ void cast_x_kernel(const float* __restrict__ in, __bf16* __restrict__ out, int n8) {
  for (int i = blockIdx.x * blockDim.x + threadIdx.x; i < n8; i += gridDim.x * blockDim.x) {
    const float4* p = (const float4*)in + (size_t)i * 2;
    float4 a = p[0], b = p[1];
    v8bf r = { (__bf16)a.x, (__bf16)a.y, (__bf16)a.z, (__bf16)a.w,
               (__bf16)b.x, (__bf16)b.y, (__bf16)b.z, (__bf16)b.w };
    *(v8bf*)(out + (size_t)i * 8) = r;
  }
}

// ---------- tiled transpose+cast: w[K][N] -> wt[N][K] bf16 ----------
__global__ __launch_bounds__(256) void transpose_cast_kernel(
    const float* __restrict__ w, __bf16* __restrict__ wt, int K, int N) {
  __shared__ __bf16 t[64 * 72];
  const int tid = threadIdx.x;
  const int n0 = blockIdx.x * 64, k0 = blockIdx.y * 64;
#pragma unroll
  for (int i = 0; i < 16; ++i) {
    int e = i * 256 + tid;
    int kk = e >> 6, nn = e & 63;
    t[nn * 72 + kk] = (__bf16)w[(size_t)(k0 + kk) * N + n0 + nn];
  }
  __syncthreads();
#pragma unroll
  for (int i = 0; i < 2; ++i) {
    int e = i * 256 + tid;
    int nn = e >> 3, kc = e & 7;
    *(v8bf*)&wt[(size_t)(n0 + nn) * K + k0 + kc * 8] = *(const v8bf*)&t[nn * 72 + kc * 8];
  }
}

// ---------- fused: qkv GEMM + rope + windowed attention ----------
// block: 256 thr (4 waves). tile: 128 tokens (2 windows) x 192 cols (2 heads).
// wave w: window wl=w>>1, head-local hl=w&1 -> owns 64 tok x 96 cols, and the
// full attention for its (window, head).
// grid (8, 256); XCD-chunked remap inside: hp = by&7, mt = (by&~7)|bx, so the
// 8 blocks sharing an A-tile sit at linear ids spaced 8 apart (same XCD under
// the %8 round-robin) and within one 64-id launch window -> A-tile L2 reuse.
// LDS: staging As[0,16384) Bs[16384,40960); after K-loop: 4 regions x 12288 B
//   { q 64x32 | k 64x32 | v 32x64 }, all power-of-2 pitch with XOR
//   group-of-8 swizzles (bank-uniform reads). P (64x64, swizzled) aliases
//   the dead q+k area of the own region. 49152 B total -> 3 blocks/CU.
#define REG_STRIDE 12288

__global__ __launch_bounds__(256, 3) void gemm_qkv_attn(
    const __bf16* __restrict__ A,    // [M_TOT][512] bf16 (token order)
    const __bf16* __restrict__ Bt,   // [1536][512] bf16
    const float* __restrict__ bias,  // [1536]
    __bf16* __restrict__ attn_out)   // [512*64][512] window-row order
{
  __shared__ __align__(16) char smem[49152];
  __bf16* As = (__bf16*)smem;
  __bf16* Bs = (__bf16*)(smem + 16384);

  const int tid  = threadIdx.x;
  const int lane = tid & 63;
  const int wave = tid >> 6;
  const int lrow = lane & 15, quad = lane >> 4;
  // XCD-chunked work remap (bijective): same-mt blocks share an XCD L2.
  const int hp   = blockIdx.y & 7;               // head pair 0..7
  const int mt   = (blockIdx.y & ~7) | blockIdx.x;  // m-tile 0..255
  const int wl   = wave >> 1, hl = wave & 1;
  const int head = hp * 2 + hl;

  // window token bases
  int mbase[2];
#pragma unroll
  for (int l = 0; l < 2; ++l) {
    int w  = mt * 2 + l;
    int b  = w >> 6, Wr = (w >> 3) & 7, Wc = w & 7;
    mbase[l] = b * 4096 + Wr * 512 + Wc * 8;
  }

  // hoisted staging pointers (advance by 64 per K-iter)
  const __bf16* aptr[4]; __bf16* adst[4];
  const __bf16* bptr[6]; __bf16* bdst[6];
#pragma unroll
  for (int i = 0; i < 4; ++i) {
    int s = i * 256 + tid;
    int row = s >> 3, c = s & 7, qc = c ^ (row & 7);
    int tok = row & 63;
    int m = mbase[row >> 6] + ((tok >> 3) << 6) + (tok & 7);
    aptr[i] = A + (size_t)m * KDIM + qc * 8;
    adst[i] = &As[(i * 256 + (tid & ~63)) * 8];
  }
#pragma unroll
  for (int i = 0; i < 6; ++i) {
    int s = i * 256 + tid;
    int rl = s >> 3, c = s & 7, qc = c ^ (rl & 7);
    int sel = rl >> 6, rem = rl & 63;
    int grow = sel * 512 + (hp * 2 + (rem >> 5)) * 32 + (rem & 31);
    bptr[i] = Bt + (size_t)grow * KDIM + qc * 8;
    bdst[i] = &Bs[(i * 256 + (tid & ~63)) * 8];
  }

  v4f acc[4][6] = {};

  for (int k0 = 0; k0 < KDIM; k0 += 64) {
#pragma unroll
    for (int i = 0; i < 4; ++i) { async_copy16(aptr[i], adst[i]); aptr[i] += 64; }
#pragma unroll
    for (int i = 0; i < 6; ++i) { async_copy16(bptr[i], bdst[i]); bptr[i] += 64; }
    __syncthreads();
#pragma unroll
    for (int kb = 0; kb < 2; ++kb) {
      int sx = (((kb << 2) | quad) ^ (lrow & 7)) * 8;
      v8bf af[4], bfr[6];
#pragma unroll
      for (int mi = 0; mi < 4; ++mi)
        af[mi] = *(const v8bf*)&As[(wl * 64 + mi * 16 + lrow) * 64 + sx];
#pragma unroll
      for (int j = 0; j < 6; ++j)
        bfr[j] = *(const v8bf*)&Bs[((j >> 1) * 64 + hl * 32 + (j & 1) * 16 + lrow) * 64 + sx];
#pragma unroll
      for (int mi = 0; mi < 4; ++mi)
#pragma unroll
        for (int j = 0; j < 6; ++j)
          acc[mi][j] = __builtin_amdgcn_mfma_f32_16x16x32_bf16(af[mi], bfr[j], acc[mi][j], 0, 0, 0);
    }
    __syncthreads();   // last iter: also protects region aliasing below
  }

  // ---- epilogue: bias + rope -> wave-private LDS region (no barriers) ----
  // qL/kL: [64 tok][32 hd], pitch 32, hd-group swizzle g^=((tok>>2)&3)
  // vL:    [32 hd][64 tok], pitch 64, tok-group swizzle g^=(hd&7)
  __bf16* reg = (__bf16*)(smem + wave * REG_STRIDE);
  __bf16* qL = reg;
  __bf16* kL = reg + 64 * 32;
  __bf16* vL = reg + 2 * 64 * 32;

  // Hoisted sincos: angle p*invf takes only 4 distinct values per lane per
  // axis, identical for q and k:
  //   hd<16 : p = tok>>3 = mi*2 + (quad>>1)    (independent of r)
  //   hd>=16: p = tok&7  = (quad&1)*4 + r      (independent of mi)
  // invf = c_invf[lrow&7] for both nh halves. 8 sincos replace 64.
  {
    const float invf = c_invf[lrow & 7];
    float cvh[4], svh[4], cvw[4], svw[4];
#pragma unroll
    for (int mi = 0; mi < 4; ++mi)
      __sincosf((float)(mi * 2 + (quad >> 1)) * invf, &svh[mi], &cvh[mi]);
#pragma unroll
    for (int r = 0; r < 4; ++r)
      __sincosf((float)((quad & 1) * 4 + r) * invf, &svw[r], &cvw[r]);

#pragma unroll
    for (int j = 0; j < 4; ++j) {          // q (j 0,1), k (j 2,3)
      int sel = j >> 1, nh = j & 1;
      int hd  = nh * 16 + lrow;
      int g   = nh * 2 + (lrow >> 3);      // hd-group (0..3)
      float bv = bias[sel * 512 + head * 32 + hd];
      __bf16* dst = sel ? kL : qL;
#pragma unroll
      for (int mi = 0; mi < 4; ++mi) {
#pragma unroll
        for (int r = 0; r < 4; ++r) {
          int tok = mi * 16 + quad * 4 + r;
          float val = acc[mi][j][r] + bv;
          float partner = __shfl_xor(val, 8);
          float cv = nh ? cvw[r] : cvh[mi];
          float sv = nh ? svw[r] : svh[mi];
          float rh = (lrow & 8) ? partner : -partner;
          val = val * cv + rh * sv;
          if (sel == 0) val *= 0.17677669529663689f;
          // (tok>>2)&3 == quad here
          dst[tok * 32 + ((g ^ quad) << 3) + (lrow & 7)] = (__bf16)val;
        }
      }
    }
  }
#pragma unroll
  for (int j = 4; j < 6; ++j) {          // v transposed [hd][tok]
    int hd = (j - 4) * 16 + lrow;        // 0..31; hd&7 == lrow&7
    float bv = bias[1024 + head * 32 + hd];
#pragma unroll
    for (int mi = 0; mi < 4; ++mi) {
      v4bf pk;
#pragma unroll
      for (int r = 0; r < 4; ++r) pk[r] = (__bf16)(acc[mi][j][r] + bv);
      int gt = mi * 2 + (quad >> 1);     // tok-group of tok0 = mi*16+quad*4
      *(v4bf*)&vL[hd * 64 + ((gt ^ (lrow & 7)) << 3) + (quad & 1) * 4] = pk;
    }
  }

  // ---- attention (wave-private) ----
  const int sq = (quad ^ (lrow >> 2)) << 3;   // q/k read swizzle (row-const)
  v8bf qf[4], kf[4];
#pragma unroll
  for (int mi = 0; mi < 4; ++mi)
    qf[mi] = *(const v8bf*)&qL[(mi * 16 + lrow) * 32 + sq];
#pragma unroll
  for (int ni = 0; ni < 4; ++ni)
    kf[ni] = *(const v8bf*)&kL[(ni * 16 + lrow) * 32 + sq];

  v4f S[4][4] = {};
#pragma unroll
  for (int mi = 0; mi < 4; ++mi)
#pragma unroll
    for (int ni = 0; ni < 4; ++ni)
      S[mi][ni] = __builtin_amdgcn_mfma_f32_16x16x32_bf16(qf[mi], kf[ni], S[mi][ni], 0, 0, 0);

#pragma unroll
  for (int mi = 0; mi < 4; ++mi) {
#pragma unroll
    for (int r = 0; r < 4; ++r) {
      float mx = S[mi][0][r];
#pragma unroll
      for (int ni = 1; ni < 4; ++ni) mx = fmaxf(mx, S[mi][ni][r]);
      for (int d = 1; d < 16; d <<= 1) mx = fmaxf(mx, __shfl_xor(mx, d));
      float sum = 0.f;
#pragma unroll
      for (int ni = 0; ni < 4; ++ni) {
        float e = __expf(S[mi][ni][r] - mx);
        S[mi][ni][r] = e; sum += e;
      }
      for (int d = 1; d < 16; d <<= 1) sum += __shfl_xor(sum, d);
      float inv = 1.f / sum;
#pragma unroll
      for (int ni = 0; ni < 4; ++ni) S[mi][ni][r] *= inv;
    }
  }

  // P (C-layout -> A-layout) through own region (aliases dead q+k)
  // P: [64 tok][64 col], pitch 64, col-group swizzle g^=(tok&7)
  __bf16* P = reg;
#pragma unroll
  for (int mi = 0; mi < 4; ++mi)
#pragma unroll
    for (int ni = 0; ni < 4; ++ni)
#pragma unroll
      for (int r = 0; r < 4; ++r) {
        int tok = mi * 16 + quad * 4 + r;
        int gc  = ni * 2 + (lrow >> 3);
        P[tok * 64 + ((gc ^ (tok & 7)) << 3) + (lrow & 7)] = (__bf16)S[mi][ni][r];
      }

  v8bf pf[4][2], vf[2][2];
#pragma unroll
  for (int mi = 0; mi < 4; ++mi)
#pragma unroll
    for (int kc = 0; kc < 2; ++kc) {
      int row = mi * 16 + lrow;          // row&7 == lrow&7
      pf[mi][kc] = *(const v8bf*)&P[row * 64 + (((kc * 4 + quad) ^ (lrow & 7)) << 3)];
    }
#pragma unroll
  for (int kc = 0; kc < 2; ++kc)
#pragma unroll
    for (int nj = 0; nj < 2; ++nj) {
      int hd = nj * 16 + lrow;           // hd&7 == lrow&7
      vf[kc][nj] = *(const v8bf*)&vL[hd * 64 + (((kc * 4 + quad) ^ (lrow & 7)) << 3)];
    }

  v4f o[4][2] = {};
#pragma unroll
  for (int mi = 0; mi < 4; ++mi)
#pragma unroll
    for (int nj = 0; nj < 2; ++nj)
#pragma unroll
      for (int kc = 0; kc < 2; ++kc)
        o[mi][nj] = __builtin_amdgcn_mfma_f32_16x16x32_bf16(pf[mi][kc], vf[kc][nj], o[mi][nj], 0, 0, 0);

  const int gwin = mt * 2 + wl;
#pragma unroll
  for (int mi = 0; mi < 4; ++mi)
#pragma unroll
    for (int nj = 0; nj < 2; ++nj)
#pragma unroll
      for (int r = 0; r < 4; ++r) {
        int tok = mi * 16 + quad * 4 + r;
        int ch  = head * 32 + nj * 16 + lrow;
        attn_out[((size_t)gwin * 64 + tok) * 512 + ch] = (__bf16)o[mi][nj][r];
      }
}

// ---------- GEMM2: out = attn_out @ proj_w + b, permuted store ----------
// 128x128 tile, 4 waves, wave = 32 rows x 128 cols. grid (4, 256) = 1024
// blocks (4 blocks/CU of work, ~3 resident; was 2). XCD-bijective remap:
// lin = bx + 4*by; xcd = lin&7; idx = lin>>3; m_blk = xcd*32 + (idx>>2),
// n_blk = idx&3 -> the 4 n-sharers of each A-panel sit on ONE XCD L2, so
// A (32 MB) is HBM-fetched ~once instead of ~4x.
__global__ __launch_bounds__(256, 3) void gemm_proj(
    const __bf16* __restrict__ A,    // [M_TOT][512] window-row order
    const __bf16* __restrict__ Bt,   // [512][512]
    const float* __restrict__ bias,  // [512]
    float* __restrict__ out)         // [8][64][64][512] spatial
{
  __shared__ __align__(16) char smem[32768];
  __bf16* As = (__bf16*)smem;                  // 128x64
  __bf16* Bs = (__bf16*)(smem + 16384);        // 128x64
  const int tid  = threadIdx.x;
  const int lane = tid & 63;
  const int wave = tid >> 6;
  const int lrow = lane & 15, quad = lane >> 4;

  const int lin = blockIdx.x + blockIdx.y * 4;
  const int xcd = lin & 7, idx = lin >> 3;
  const int m0  = (xcd * 32 + (idx >> 2)) * 128;
  const int n0  = (idx & 3) * 128;

  const __bf16* aptr[4]; __bf16* adst[4];
  const __bf16* bptr[4]; __bf16* bdst[4];
#pragma unroll
  for (int i = 0; i < 4; ++i) {
    int s = i * 256 + tid;
    int row = s >> 3, c = s & 7, qc = c ^ (row & 7);
    aptr[i] = A + (size_t)(m0 + row) * KDIM + qc * 8;
    adst[i] = &As[(i * 256 + (tid & ~63)) * 8];
    bptr[i] = Bt + (size_t)(n0 + row) * KDIM + qc * 8;
    bdst[i] = &Bs[(i * 256 + (tid & ~63)) * 8];
  }

  v4f acc[2][8] = {};

  for (int k0 = 0; k0 < KDIM; k0 += 64) {
#pragma unroll
    for (int i = 0; i < 4; ++i) { async_copy16(aptr[i], adst[i]); aptr[i] += 64; }
#pragma unroll
    for (int i = 0; i < 4; ++i) { async_copy16(bptr[i], bdst[i]); bptr[i] += 64; }
    __syncthreads();
#pragma unroll
    for (int kb = 0; kb < 2; ++kb) {
      int sx = (((kb << 2) | quad) ^ (lrow & 7)) * 8;
      v8bf af[2], bfr[8];
#pragma unroll
      for (int mi = 0; mi < 2; ++mi)
        af[mi] = *(const v8bf*)&As[(wave * 32 + mi * 16 + lrow) * 64 + sx];
#pragma unroll
      for (int ni = 0; ni < 8; ++ni)
        bfr[ni] = *(const v8bf*)&Bs[(ni * 16 + lrow) * 64 + sx];
#pragma unroll
      for (int mi = 0; mi < 2; ++mi)
#pragma unroll
        for (int ni = 0; ni < 8; ++ni)
          acc[mi][ni] = __builtin_amdgcn_mfma_f32_16x16x32_bf16(af[mi], bfr[ni], acc[mi][ni], 0, 0, 0);
    }
    __syncthreads();
  }

  const int mb = m0 + wave * 32;
#pragma unroll
  for (int ni = 0; ni < 8; ++ni) {
    int n = n0 + ni * 16 + lrow;
    float bv = bias[n];
#pragma unroll
    for (int mi = 0; mi < 2; ++mi) {
#pragma unroll
      for (int r = 0; r < 4; ++r) {
        int m    = mb + mi * 16 + quad * 4 + r;
        int win  = m >> 6, tok = m & 63;
        int bb   = win >> 6;
        int hblk = (win >> 3) & 7, wblk = win & 7;
        int h    = hblk * 8 + (tok >> 3);
        int w    = wblk * 8 + (tok & 7);
        out[(((size_t)bb * 64 + h) * 64 + w) * 512 + n] = acc[mi][ni][r] + bv;
      }
    }
  }
}

// ---------- launcher ----------
extern "C" void kernel_launch(void* const* d_in, const int* in_sizes, int n_in,
                              void* d_out, int out_size, void* d_ws, size_t ws_size,
                              hipStream_t stream) {
  (void)in_sizes; (void)n_in; (void)out_size; (void)ws_size;
  const float* x      = (const float*)d_in[0];
  const float* qkv_w  = (const float*)d_in[1];
  const float* qkv_b  = (const float*)d_in[2];
  // d_in[3]=kv_w, d_in[4]=kv_b: dead code in reference (hy_kv unused)
  const float* proj_w = (const float*)d_in[5];
  const float* proj_b = (const float*)d_in[6];
  float* out = (float*)d_out;

  char* ws = (char*)d_ws;
  size_t off = 0;
  auto alloc = [&](size_t bytes) {
    char* p = ws + off;
    off += (bytes + 255) & ~(size_t)255;
    return (void*)p;
  };
  __bf16* xb       = (__bf16*)alloc((size_t)M_TOT * KDIM * 2);
  __bf16* qkv_wt   = (__bf16*)alloc((size_t)NQKV * KDIM * 2);
  __bf16* proj_wt  = (__bf16*)alloc((size_t)KDIM * KDIM * 2);
  __bf16* attn_out = (__bf16*)alloc((size_t)M_TOT * KDIM * 2);

  cast_x_kernel<<<dim3(2048), dim3(256), 0, stream>>>(
      x, xb, M_TOT * KDIM / 8);
  transpose_cast_kernel<<<dim3(NQKV / 64, KDIM / 64), dim3(256), 0, stream>>>(
      qkv_w, qkv_wt, KDIM, NQKV);
  transpose_cast_kernel<<<dim3(NPROJ / 64, KDIM / 64), dim3(256), 0, stream>>>(
      proj_w, proj_wt, KDIM, NPROJ);

  gemm_qkv_attn<<<dim3(8, 256), dim3(256), 0, stream>>>(
      xb, qkv_wt, qkv_b, attn_out);

  gemm_proj<<<dim3(4, 256), dim3(256), 0, stream>>>(
      attn_out, proj_wt, proj_b, out);
}

// Round 4
// 219.758 us; speedup vs baseline: 1.1910x; 1.0371x over previous
//
#include <hip/hip_runtime.h>
#include <cstdint>
#include <cstddef>

// ---------- types ----------
typedef float v4f  __attribute__((ext_vector_type(4)));
typedef __bf16 v8bf __attribute__((ext_vector_type(8)));
typedef __bf16 v4bf __attribute__((ext_vector_type(4)));

#define M_TOT 32768   // 8*64*64 tokens
#define KDIM  512
#define NQKV  1536
#define NPROJ 512

__device__ __constant__ float c_invf[8] = {
  1.f, 0.31622776601683794f, 0.1f, 0.031622776601683794f,
  0.01f, 0.0031622776601683794f, 0.001f, 0.00031622776601683794f };

__device__ __forceinline__ void async_copy16(const void* g, void* l) {
  __builtin_amdgcn_global_load_lds((const __attribute__((address_space(1))) void*)g,
                                   (__attribute__((address_space(3))) void*)l, 16, 0, 0);
}

// ---------- cast x -> bf16 (grid-stride) ----------
__global__ void cast_x_kernel(const float* __restrict__ in, __bf16* __restrict__ out, int n8) {
  for (int i = blockIdx.x * blockDim.x + threadIdx.x; i < n8; i += gridDim.x * blockDim.x) {
    const float4* p = (const float4*)in + (size_t)i * 2;
    float4 a = p[0], b = p[1];
    v8bf r = { (__bf16)a.x, (__bf16)a.y, (__bf16)a.z, (__bf16)a.w,
               (__bf16)b.x, (__bf16)b.y, (__bf16)b.z, (__bf16)b.w };
    *(v8bf*)(out + (size_t)i * 8) = r;
  }
}

// ---------- tiled transpose+cast: w[K][N] -> wt[N][K] bf16 ----------
__global__ __launch_bounds__(256) void transpose_cast_kernel(
    const float* __restrict__ w, __bf16* __restrict__ wt, int K, int N) {
  __shared__ __bf16 t[64 * 72];
  const int tid = threadIdx.x;
  const int n0 = blockIdx.x * 64, k0 = blockIdx.y * 64;
#pragma unroll
  for (int i = 0; i < 16; ++i) {
    int e = i * 256 + tid;
    int kk = e >> 6, nn = e & 63;
    t[nn * 72 + kk] = (__bf16)w[(size_t)(k0 + kk) * N + n0 + nn];
  }
  __syncthreads();
#pragma unroll
  for (int i = 0; i < 2; ++i) {
    int e = i * 256 + tid;
    int nn = e >> 3, kc = e & 7;
    *(v8bf*)&wt[(size_t)(n0 + nn) * K + k0 + kc * 8] = *(const v8bf*)&t[nn * 72 + kc * 8];
  }
}

// ---------- fused: qkv GEMM + rope + windowed attention ----------
// block: 256 thr (4 waves). tile: 128 tokens (2 windows) x 192 cols (2 heads).
// wave w: window wl=w>>1, head-local hl=w&1 -> owns 64 tok x 96 cols, and the
// full attention for its (window, head).
// grid (8, 256); XCD-chunked remap: hp = by&7, mt = (by&~7)|bx (A-tile L2 reuse).
// LDS: staging As[0,16384) Bs[16384,40960); after K-loop: 4 regions x 12288 B
//   { q 64x32 | k 64x32 | v 32x64 }, XOR group-of-8 swizzles. P (64x64,
//   swizzled) aliases dead q+k of own region. 49152 B -> 3 blocks/CU.
// OPERAND-SWAPPED MFMAs downstream of the GEMM:
//   S = mfma(kf, qf): lane holds 16 k-vals for ONE q -> row-reduce is
//     15 in-reg fmax + 2 shfl (was 128 shfl/wave total).
//   P[k][q] per lane has 4 consecutive k -> v4bf P-stores (16 vs 64).
//   O^T = mfma(vf, pf): lane holds 4 consecutive ch -> v4bf out (8 vs 32).
#define REG_STRIDE 12288

__global__ __launch_bounds__(256, 3) void gemm_qkv_attn(
    const __bf16* __restrict__ A,    // [M_TOT][512] bf16 (token order)
    const __bf16* __restrict__ Bt,   // [1536][512] bf16
    const float* __restrict__ bias,  // [1536]
    __bf16* __restrict__ attn_out)   // [512*64][512] window-row order
{
  __shared__ __align__(16) char smem[49152];
  __bf16* As = (__bf16*)smem;
  __bf16* Bs = (__bf16*)(smem + 16384);

  const int tid  = threadIdx.x;
  const int lane = tid & 63;
  const int wave = tid >> 6;
  const int lrow = lane & 15, quad = lane >> 4;
  // XCD-chunked work remap (bijective): same-mt blocks share an XCD L2.
  const int hp   = blockIdx.y & 7;               // head pair 0..7
  const int mt   = (blockIdx.y & ~7) | blockIdx.x;  // m-tile 0..255
  const int wl   = wave >> 1, hl = wave & 1;
  const int head = hp * 2 + hl;

  // window token bases
  int mbase[2];
#pragma unroll
  for (int l = 0; l < 2; ++l) {
    int w  = mt * 2 + l;
    int b  = w >> 6, Wr = (w >> 3) & 7, Wc = w & 7;
    mbase[l] = b * 4096 + Wr * 512 + Wc * 8;
  }

  // hoisted staging pointers (advance by 64 per K-iter)
  const __bf16* aptr[4]; __bf16* adst[4];
  const __bf16* bptr[6]; __bf16* bdst[6];
#pragma unroll
  for (int i = 0; i < 4; ++i) {
    int s = i * 256 + tid;
    int row = s >> 3, c = s & 7, qc = c ^ (row & 7);
    int tok = row & 63;
    int m = mbase[row >> 6] + ((tok >> 3) << 6) + (tok & 7);
    aptr[i] = A + (size_t)m * KDIM + qc * 8;
    adst[i] = &As[(i * 256 + (tid & ~63)) * 8];
  }
#pragma unroll
  for (int i = 0; i < 6; ++i) {
    int s = i * 256 + tid;
    int rl = s >> 3, c = s & 7, qc = c ^ (rl & 7);
    int sel = rl >> 6, rem = rl & 63;
    int grow = sel * 512 + (hp * 2 + (rem >> 5)) * 32 + (rem & 31);
    bptr[i] = Bt + (size_t)grow * KDIM + qc * 8;
    bdst[i] = &Bs[(i * 256 + (tid & ~63)) * 8];
  }

  v4f acc[4][6] = {};

  for (int k0 = 0; k0 < KDIM; k0 += 64) {
#pragma unroll
    for (int i = 0; i < 4; ++i) { async_copy16(aptr[i], adst[i]); aptr[i] += 64; }
#pragma unroll
    for (int i = 0; i < 6; ++i) { async_copy16(bptr[i], bdst[i]); bptr[i] += 64; }
    __syncthreads();
#pragma unroll
    for (int kb = 0; kb < 2; ++kb) {
      int sx = (((kb << 2) | quad) ^ (lrow & 7)) * 8;
      v8bf af[4], bfr[6];
#pragma unroll
      for (int mi = 0; mi < 4; ++mi)
        af[mi] = *(const v8bf*)&As[(wl * 64 + mi * 16 + lrow) * 64 + sx];
#pragma unroll
      for (int j = 0; j < 6; ++j)
        bfr[j] = *(const v8bf*)&Bs[((j >> 1) * 64 + hl * 32 + (j & 1) * 16 + lrow) * 64 + sx];
#pragma unroll
      for (int mi = 0; mi < 4; ++mi)
#pragma unroll
        for (int j = 0; j < 6; ++j)
          acc[mi][j] = __builtin_amdgcn_mfma_f32_16x16x32_bf16(af[mi], bfr[j], acc[mi][j], 0, 0, 0);
    }
    __syncthreads();   // last iter: also protects region aliasing below
  }

  // ---- epilogue: bias + rope -> wave-private LDS region (no barriers) ----
  // qL/kL: [64 tok][32 hd], pitch 32, hd-group swizzle g^=((tok>>2)&3)
  // vL:    [32 hd][64 tok], pitch 64, tok-group swizzle g^=(hd&7)
  __bf16* reg = (__bf16*)(smem + wave * REG_STRIDE);
  __bf16* qL = reg;
  __bf16* kL = reg + 64 * 32;
  __bf16* vL = reg + 2 * 64 * 32;

  // Hoisted sincos: angle p*invf takes only 4 distinct values per lane per
  // axis, identical for q and k:
  //   hd<16 : p = tok>>3 = mi*2 + (quad>>1)    (independent of r)
  //   hd>=16: p = tok&7  = (quad&1)*4 + r      (independent of mi)
  // invf = c_invf[lrow&7] for both nh halves. 8 sincos replace 64.
  {
    const float invf = c_invf[lrow & 7];
    float cvh[4], svh[4], cvw[4], svw[4];
#pragma unroll
    for (int mi = 0; mi < 4; ++mi)
      __sincosf((float)(mi * 2 + (quad >> 1)) * invf, &svh[mi], &cvh[mi]);
#pragma unroll
    for (int r = 0; r < 4; ++r)
      __sincosf((float)((quad & 1) * 4 + r) * invf, &svw[r], &cvw[r]);

#pragma unroll
    for (int j = 0; j < 4; ++j) {          // q (j 0,1), k (j 2,3)
      int sel = j >> 1, nh = j & 1;
      int hd  = nh * 16 + lrow;
      int g   = nh * 2 + (lrow >> 3);      // hd-group (0..3)
      float bv = bias[sel * 512 + head * 32 + hd];
      __bf16* dst = sel ? kL : qL;
#pragma unroll
      for (int mi = 0; mi < 4; ++mi) {
#pragma unroll
        for (int r = 0; r < 4; ++r) {
          int tok = mi * 16 + quad * 4 + r;
          float val = acc[mi][j][r] + bv;
          float partner = __shfl_xor(val, 8);
          float cv = nh ? cvw[r] : cvh[mi];
          float sv = nh ? svw[r] : svh[mi];
          float rh = (lrow & 8) ? partner : -partner;
          val = val * cv + rh * sv;
          if (sel == 0) val *= 0.17677669529663689f;
          // (tok>>2)&3 == quad here
          dst[tok * 32 + ((g ^ quad) << 3) + (lrow & 7)] = (__bf16)val;
        }
      }
    }
  }
#pragma unroll
  for (int j = 4; j < 6; ++j) {          // v transposed [hd][tok]
    int hd = (j - 4) * 16 + lrow;        // 0..31; hd&7 == lrow&7
    float bv = bias[1024 + head * 32 + hd];
#pragma unroll
    for (int mi = 0; mi < 4; ++mi) {
      v4bf pk;
#pragma unroll
      for (int r = 0; r < 4; ++r) pk[r] = (__bf16)(acc[mi][j][r] + bv);
      int gt = mi * 2 + (quad >> 1);     // tok-group of tok0 = mi*16+quad*4
      *(v4bf*)&vL[hd * 64 + ((gt ^ (lrow & 7)) << 3) + (quad & 1) * 4] = pk;
    }
  }

  // ---- attention (wave-private) ----
  const int sq = (quad ^ (lrow >> 2)) << 3;   // q/k read swizzle (row-const)
  v8bf qf[4], kf[4];
#pragma unroll
  for (int mi = 0; mi < 4; ++mi)
    qf[mi] = *(const v8bf*)&qL[(mi * 16 + lrow) * 32 + sq];
#pragma unroll
  for (int ni = 0; ni < 4; ++ni)
    kf[ni] = *(const v8bf*)&kL[(ni * 16 + lrow) * 32 + sq];

  // SWAPPED: S[ni][mi][r] = S[q = mi*16+lrow][k = ni*16+quad*4+r]
  v4f S[4][4] = {};
#pragma unroll
  for (int ni = 0; ni < 4; ++ni)
#pragma unroll
    for (int mi = 0; mi < 4; ++mi)
      S[ni][mi] = __builtin_amdgcn_mfma_f32_16x16x32_bf16(kf[ni], qf[mi], S[ni][mi], 0, 0, 0);

  // softmax over k: 16 in-reg values + 2 cross-quad shuffles per q-row
#pragma unroll
  for (int mi = 0; mi < 4; ++mi) {
    float mx = S[0][mi][0];
#pragma unroll
    for (int ni = 0; ni < 4; ++ni)
#pragma unroll
      for (int r = 0; r < 4; ++r) mx = fmaxf(mx, S[ni][mi][r]);
    mx = fmaxf(mx, __shfl_xor(mx, 16));
    mx = fmaxf(mx, __shfl_xor(mx, 32));
    float sum = 0.f;
#pragma unroll
    for (int ni = 0; ni < 4; ++ni)
#pragma unroll
      for (int r = 0; r < 4; ++r) {
        float e = __expf(S[ni][mi][r] - mx);
        S[ni][mi][r] = e; sum += e;
      }
    sum += __shfl_xor(sum, 16);
    sum += __shfl_xor(sum, 32);
    float inv = 1.f / sum;
#pragma unroll
    for (int ni = 0; ni < 4; ++ni)
#pragma unroll
      for (int r = 0; r < 4; ++r) S[ni][mi][r] *= inv;
  }

  // P[q][k] via own region (aliases dead q+k); 4 consecutive k per lane
  // P: pitch 64, col-group swizzle g^=(q&7); q&7 == lrow&7
  __bf16* P = reg;
#pragma unroll
  for (int mi = 0; mi < 4; ++mi) {
    int q = mi * 16 + lrow;
#pragma unroll
    for (int ni = 0; ni < 4; ++ni) {
      v4bf pk;
#pragma unroll
      for (int r = 0; r < 4; ++r) pk[r] = (__bf16)S[ni][mi][r];
      int g = ni * 2 + (quad >> 1);
      *(v4bf*)&P[q * 64 + ((g ^ (lrow & 7)) << 3) + (quad & 1) * 4] = pk;
    }
  }

  v8bf pf[4][2], vf[2][2];
#pragma unroll
  for (int mi = 0; mi < 4; ++mi)
#pragma unroll
    for (int kc = 0; kc < 2; ++kc) {
      int row = mi * 16 + lrow;          // row&7 == lrow&7
      pf[mi][kc] = *(const v8bf*)&P[row * 64 + (((kc * 4 + quad) ^ (lrow & 7)) << 3)];
    }
#pragma unroll
  for (int kc = 0; kc < 2; ++kc)
#pragma unroll
    for (int nj = 0; nj < 2; ++nj) {
      int hd = nj * 16 + lrow;           // hd&7 == lrow&7
      vf[kc][nj] = *(const v8bf*)&vL[hd * 64 + (((kc * 4 + quad) ^ (lrow & 7)) << 3)];
    }

  // SWAPPED: o[nj][mi][r] = O[q = mi*16+lrow][ch = nj*16+quad*4+r]
  v4f o[2][4] = {};
#pragma unroll
  for (int nj = 0; nj < 2; ++nj)
#pragma unroll
    for (int mi = 0; mi < 4; ++mi)
#pragma unroll
      for (int kc = 0; kc < 2; ++kc)
        o[nj][mi] = __builtin_amdgcn_mfma_f32_16x16x32_bf16(vf[kc][nj], pf[mi][kc], o[nj][mi], 0, 0, 0);

  const int gwin = mt * 2 + wl;
#pragma unroll
  for (int mi = 0; mi < 4; ++mi) {
    size_t rowoff = ((size_t)gwin * 64 + mi * 16 + lrow) * 512 + head * 32 + quad * 4;
#pragma unroll
    for (int nj = 0; nj < 2; ++nj) {
      v4bf pk;
#pragma unroll
      for (int r = 0; r < 4; ++r) pk[r] = (__bf16)o[nj][mi][r];
      *(v4bf*)&attn_out[rowoff + nj * 16] = pk;
    }
  }
}

// ---------- GEMM2: out = attn_out @ proj_w + b, permuted store ----------
// 128x128 tile, 4 waves, wave = 32 rows x 128 cols. grid (4, 256) = 1024
// blocks. XCD-bijective remap: lin = bx + 4*by; xcd = lin&7; idx = lin>>3;
// m_blk = xcd*32 + (idx>>2), n_blk = idx&3 -> A-panel sharers on one XCD L2.
// SWAPPED MFMA: acc[ni][mi][r] = C[m = 16mi+lrow][n = 16ni+4quad+r] -> the
// permuted f32 store is float4-wide (16 stores vs 64 dwords), row address
// computed once per mi.
__global__ __launch_bounds__(256, 3) void gemm_proj(
    const __bf16* __restrict__ A,    // [M_TOT][512] window-row order
    const __bf16* __restrict__ Bt,   // [512][512]
    const float* __restrict__ bias,  // [512]
    float* __restrict__ out)         // [8][64][64][512] spatial
{
  __shared__ __align__(16) char smem[32768];
  __bf16* As = (__bf16*)smem;                  // 128x64
  __bf16* Bs = (__bf16*)(smem + 16384);        // 128x64
  const int tid  = threadIdx.x;
  const int lane = tid & 63;
  const int wave = tid >> 6;
  const int lrow = lane & 15, quad = lane >> 4;

  const int lin = blockIdx.x + blockIdx.y * 4;
  const int xcd = lin & 7, idx = lin >> 3;
  const int m0  = (xcd * 32 + (idx >> 2)) * 128;
  const int n0  = (idx & 3) * 128;

  const __bf16* aptr[4]; __bf16* adst[4];
  const __bf16* bptr[4]; __bf16* bdst[4];
#pragma unroll
  for (int i = 0; i < 4; ++i) {
    int s = i * 256 + tid;
    int row = s >> 3, c = s & 7, qc = c ^ (row & 7);
    aptr[i] = A + (size_t)(m0 + row) * KDIM + qc * 8;
    adst[i] = &As[(i * 256 + (tid & ~63)) * 8];
    bptr[i] = Bt + (size_t)(n0 + row) * KDIM + qc * 8;
    bdst[i] = &Bs[(i * 256 + (tid & ~63)) * 8];
  }

  v4f acc[8][2] = {};

  for (int k0 = 0; k0 < KDIM; k0 += 64) {
#pragma unroll
    for (int i = 0; i < 4; ++i) { async_copy16(aptr[i], adst[i]); aptr[i] += 64; }
#pragma unroll
    for (int i = 0; i < 4; ++i) { async_copy16(bptr[i], bdst[i]); bptr[i] += 64; }
    __syncthreads();
#pragma unroll
    for (int kb = 0; kb < 2; ++kb) {
      int sx = (((kb << 2) | quad) ^ (lrow & 7)) * 8;
      v8bf af[2], bfr[8];
#pragma unroll
      for (int mi = 0; mi < 2; ++mi)
        af[mi] = *(const v8bf*)&As[(wave * 32 + mi * 16 + lrow) * 64 + sx];
#pragma unroll
      for (int ni = 0; ni < 8; ++ni)
        bfr[ni] = *(const v8bf*)&Bs[(ni * 16 + lrow) * 64 + sx];
#pragma unroll
      for (int ni = 0; ni < 8; ++ni)
#pragma unroll
        for (int mi = 0; mi < 2; ++mi)
          acc[ni][mi] = __builtin_amdgcn_mfma_f32_16x16x32_bf16(bfr[ni], af[mi], acc[ni][mi], 0, 0, 0);
    }
    __syncthreads();
  }

  // bias (reused across mi)
  float4 bv[8];
#pragma unroll
  for (int ni = 0; ni < 8; ++ni)
    bv[ni] = *(const float4*)&bias[n0 + ni * 16 + quad * 4];

  const int mb = m0 + wave * 32;
#pragma unroll
  for (int mi = 0; mi < 2; ++mi) {
    int m    = mb + mi * 16 + lrow;
    int win  = m >> 6, tok = m & 63;
    int bb   = win >> 6;
    int hblk = (win >> 3) & 7, wblk = win & 7;
    int h    = hblk * 8 + (tok >> 3);
    int w    = wblk * 8 + (tok & 7);
    float* orow = &out[(((size_t)bb * 64 + h) * 64 + w) * 512 + n0 + quad * 4];
#pragma unroll
    for (int ni = 0; ni < 8; ++ni) {
      float4 v = { acc[ni][mi][0] + bv[ni].x, acc[ni][mi][1] + bv[ni].y,
                   acc[ni][mi][2] + bv[ni].z, acc[ni][mi][3] + bv[ni].w };
      *(float4*)&orow[ni * 16] = v;
    }
  }
}

// ---------- launcher ----------
extern "C" void kernel_launch(void* const* d_in, const int* in_sizes, int n_in,
                              void* d_out, int out_size, void* d_ws, size_t ws_size,
                              hipStream_t stream) {
  (void)in_sizes; (void)n_in; (void)out_size; (void)ws_size;
  const float* x      = (const float*)d_in[0];
  const float* qkv_w  = (const float*)d_in[1];
  const float* qkv_b  = (const float*)d_in[2];
  // d_in[3]=kv_w, d_in[4]=kv_b: dead code in reference (hy_kv unused)
  const float* proj_w = (const float*)d_in[5];
  const float* proj_b = (const float*)d_in[6];
  float* out = (float*)d_out;

  char* ws = (char*)d_ws;
  size_t off = 0;
  auto alloc = [&](size_t bytes) {
    char* p = ws + off;
    off += (bytes + 255) & ~(size_t)255;
    return (void*)p;
  };
  __bf16* xb       = (__bf16*)alloc((size_t)M_TOT * KDIM * 2);
  __bf16* qkv_wt   = (__bf16*)alloc((size_t)NQKV * KDIM * 2);
  __bf16* proj_wt  = (__bf16*)alloc((size_t)KDIM * KDIM * 2);
  __bf16* attn_out = (__bf16*)alloc((size_t)M_TOT * KDIM * 2);

  cast_x_kernel<<<dim3(2048), dim3(256), 0, stream>>>(
      x, xb, M_TOT * KDIM / 8);
  transpose_cast_kernel<<<dim3(NQKV / 64, KDIM / 64), dim3(256), 0, stream>>>(
      qkv_w, qkv_wt, KDIM, NQKV);
  transpose_cast_kernel<<<dim3(NPROJ / 64, KDIM / 64), dim3(256), 0, stream>>>(
      proj_w, proj_wt, KDIM, NPROJ);

  gemm_qkv_attn<<<dim3(8, 256), dim3(256), 0, stream>>>(
      xb, qkv_wt, qkv_b, attn_out);

  gemm_proj<<<dim3(4, 256), dim3(256), 0, stream>>>(
      attn_out, proj_wt, proj_b, out);
}